// Round 8
// baseline (494.015 us; speedup 1.0000x reference)
//
#include <hip/hip_runtime.h>
#include <math.h>

#define DIM 768
#define HWS 56
#define PLANE (HWS * HWS)     // 3136
#define PLANE4 (PLANE / 4)    // 784
#define LSTRIDE 64
#define LROWS 59              // 1 underflow row + 1 top halo + 56 data + 1 bottom halo

__device__ __forceinline__ float quant_fixed(float x) {
    // floor(x/2^-16 + 0.5) * 2^-16, clipped to [-2^15, 2^15 - 1] — fp32-exact
    float t = floorf(x * 65536.0f + 0.5f);
    float r = t * (1.0f / 65536.0f);
    return fminf(fmaxf(r, -32768.0f), 32767.0f);
}

// Single-wave block: one 56x56 plane per 64-thread block.
// LDS tile padded to stride 64 with zeroed halo (rows 0,1,58 full-zero;
// cols 56..63 of data rows zero) -> branchless 3x3 stencil; a read at
// (row, col -1) lands on (row-1, col 63) which is always zero.
__global__ __launch_bounds__(64, 2) void peg_shift_dwconv(
        const float* __restrict__ x, const float* __restrict__ weight,
        const float* __restrict__ bias, float* __restrict__ out) {
    __shared__ __align__(16) float tile[LROWS * LSTRIDE];
    __shared__ float qw_s[9];
    __shared__ float bias_s;

    const int tid = threadIdx.x;           // 0..63 (one wave)
    const int plane = blockIdx.x;          // n*768 + c
    const int c = plane % DIM;

    // --- zero halo: 160 float4 = rows 0,1,58 (48) + cols 56..63 of rows 2..57 (112) ---
    for (int f = tid; f < 160; f += 64) {
        int row, col4;
        if (f < 48) { int r = f >> 4; row = (r == 2) ? 58 : r; col4 = f & 15; }
        else        { int g = f - 48; row = 2 + (g >> 1);      col4 = 14 + (g & 1); }
        *(float4*)&tile[row * LSTRIDE + col4 * 4] = float4{0.f, 0.f, 0.f, 0.f};
    }

    // --- quantize the 9 weights of this channel (round-half-even like jnp.round) ---
    if (tid < 9) {
        float wv = weight[c * 9 + tid];
        float a = fabsf(wv) + 1e-32f;
        float sh = rintf(log2f(a));
        sh = fminf(fmaxf(sh, -14.0f), 0.0f);
        float p = exp2f(sh);
        float s = (wv > 0.0f) ? 1.0f : ((wv < 0.0f) ? -1.0f : 0.0f);
        qw_s[tid] = s * p;
    }
    if (tid == 9) bias_s = bias[c];

    // --- stage + quantize the plane: 12 upfront float4 loads + 16-thread tail ---
    const float4* in4 = (const float4*)(x + (size_t)plane * PLANE);
    float4 v[12];
    #pragma unroll
    for (int k = 0; k < 12; ++k) v[k] = in4[k * 64 + tid];
    float4 vt;
    if (tid < 16) vt = in4[768 + tid];

    #pragma unroll
    for (int k = 0; k < 12; ++k) {
        int j = k * 64 + tid;
        int h = j / 14, q = j - h * 14;
        float4 w4;
        w4.x = quant_fixed(v[k].x); w4.y = quant_fixed(v[k].y);
        w4.z = quant_fixed(v[k].z); w4.w = quant_fixed(v[k].w);
        *(float4*)&tile[(h + 2) * LSTRIDE + q * 4] = w4;
    }
    if (tid < 16) {
        int j = 768 + tid;
        int h = j / 14, q = j - h * 14;
        float4 w4;
        w4.x = quant_fixed(vt.x); w4.y = quant_fixed(vt.y);
        w4.z = quant_fixed(vt.z); w4.w = quant_fixed(vt.w);
        *(float4*)&tile[(h + 2) * LSTRIDE + q * 4] = w4;
    }
    __syncthreads();

    float kk[9];
    #pragma unroll
    for (int i = 0; i < 9; ++i) kk[i] = qw_s[i];
    const float bv = bias_s;

    // --- compute: lane = (strip 0..13, band 0..3); 4 cols x 14 rows per lane,
    //     rolling 3-row window of (left b32, mid float4, right b32) LDS reads ---
    if (tid < 56) {
        const int s    = tid % 14;
        const int band = tid / 14;
        const int c0   = 4 * s;
        float* outp = out + (size_t)plane * PLANE;

        const float* rowp = tile + (band * 14 + 1) * LSTRIDE + c0;  // data row band*14-1
        float  l0 = rowp[-1];
        float4 m0 = *(const float4*)rowp;
        float  r0 = rowp[4];
        rowp += LSTRIDE;
        float  l1 = rowp[-1];
        float4 m1 = *(const float4*)rowp;
        float  r1 = rowp[4];

        #pragma unroll
        for (int i = 0; i < 14; ++i) {
            rowp += LSTRIDE;                      // data row band*14 + i + 1
            float  l2 = rowp[-1];
            float4 m2 = *(const float4*)rowp;
            float  r2 = rowp[4];
            const int h = band * 14 + i;

            float4 acc;
            acc.x = bv + kk[0]*l0   + kk[1]*m0.x + kk[2]*m0.y
                       + kk[3]*l1   + kk[4]*m1.x + kk[5]*m1.y
                       + kk[6]*l2   + kk[7]*m2.x + kk[8]*m2.y;
            acc.y = bv + kk[0]*m0.x + kk[1]*m0.y + kk[2]*m0.z
                       + kk[3]*m1.x + kk[4]*m1.y + kk[5]*m1.z
                       + kk[6]*m2.x + kk[7]*m2.y + kk[8]*m2.z;
            acc.z = bv + kk[0]*m0.y + kk[1]*m0.z + kk[2]*m0.w
                       + kk[3]*m1.y + kk[4]*m1.z + kk[5]*m1.w
                       + kk[6]*m2.y + kk[7]*m2.z + kk[8]*m2.w;
            acc.w = bv + kk[0]*m0.z + kk[1]*m0.w + kk[2]*r0
                       + kk[3]*m1.z + kk[4]*m1.w + kk[5]*r1
                       + kk[6]*m2.z + kk[7]*m2.w + kk[8]*r2;

            *(float4*)&outp[h * HWS + c0] = acc;

            l0 = l1; m0 = m1; r0 = r1;
            l1 = l2; m1 = m2; r1 = r2;
        }
    }
}

extern "C" void kernel_launch(void* const* d_in, const int* in_sizes, int n_in,
                              void* d_out, int out_size, void* d_ws, size_t ws_size,
                              hipStream_t stream) {
    const float* x = (const float*)d_in[0];
    const float* wgt = (const float*)d_in[1];
    const float* bias = (const float*)d_in[2];
    float* out = (float*)d_out;
    const int nplanes = in_sizes[0] / PLANE;   // 32*768 = 24576
    peg_shift_dwconv<<<nplanes, 64, 0, stream>>>(x, wgt, bias, out);
}